// Round 1
// baseline (69.746 us; speedup 1.0000x reference)
//
#include <hip/hip_runtime.h>
#include <limits.h>

#define BATCH 512
#define SEQ   8192
#define KLEN  8
// Priority key: (5-n)*SEQ + p. Smaller key = longer n first, then earlier p —
// matches the reference's length-major selection (n=5 > 4 > 3, first match).
#define KEY_LIMIT (3 * SEQ)

// ONE dispatch: scan + priority-select + extract.
// One block per row; 1024 thr x 8 positions = 8192 = S in a single pass.
// Key change vs prev round: the 3x int4 row loads are issued BEFORE the
// L/mask loads (clamped addressing, not guarded), removing one serial
// memory latency (L -> guard -> loads) from the critical chain. Compares
// stay guarded by the original p, so clamped threads are masked anyway.
__global__ __launch_bounds__(1024)
void ngram_fused(const int* __restrict__ num_tokens,   // [B]
                 const int* __restrict__ tokens,       // [B,S]
                 const int* __restrict__ mask,         // [B] bool as int32
                 int* __restrict__ out)                // [B,K]
{
    const int b   = blockIdx.x;
    const int tid = threadIdx.x;
    const long base = (long)b * SEQ;

    // --- issue the wide row loads FIRST, independent of L and mask --------
    // Clamp keeps the last thread in-row: p0=8184 would read to +8195.
    // Any clamped thread has every position p >= 8184 > limit3 (<= 8181),
    // so its compares are masked below -> loading shifted data is safe.
    const int p0 = tid * 8;                       // 16B-aligned window base
    const int pc = (p0 <= SEQ - 12) ? p0 : (SEQ - 12);
    const int4 va = *(const int4*)(tokens + base + pc);
    const int4 vb = *(const int4*)(tokens + base + pc + 4);
    const int4 vc = *(const int4*)(tokens + base + pc + 8);

    // Scalar row metadata — independent of the vector loads, overlap them.
    const int mk = mask[b];
    const int L  = num_tokens[b];

    __shared__ int s_best;
    if (tid == 0) s_best = INT_MAX;

    const int limit3 = L - 3 - KLEN;  // max valid p for n=3
    const int limit4 = L - 4 - KLEN;
    const int limit5 = L - 5 - KLEN;

    // Block-uniform early out: masked-off row or row too short -> all zeros.
    // (Loads above are already in flight; they retire unused — L2 hits.)
    if (mk == 0 || limit3 < 0) {
        if (tid < KLEN) out[b * KLEN + tid] = 0;
        return;                       // uniform: no barrier divergence
    }

    // L >= 11 here -> pattern indices L-5..L-1 valid. Same-address across
    // the block -> one request, broadcast. Only chain left: L -> patterns.
    const int pat0 = tokens[base + L - 5];
    const int pat1 = tokens[base + L - 4];
    const int pat2 = tokens[base + L - 3];
    const int pat3 = tokens[base + L - 2];
    const int pat4 = tokens[base + L - 1];

    int bestLocal = INT_MAX;
    if (p0 <= limit3) {               // threads fully past L skip the VALU work
        const int w[12] = { va.x, va.y, va.z, va.w,
                            vb.x, vb.y, vb.z, vb.w,
                            vc.x, vc.y, vc.z, vc.w };
        #pragma unroll
        for (int j = 0; j < 8; ++j) {
            const int p = p0 + j;
            const bool q3 = (w[j]   == pat2) & (w[j+1] == pat3) & (w[j+2] == pat4)
                            & (p <= limit3);
            const bool q4 = (w[j]   == pat1) & (w[j+1] == pat2) & (w[j+2] == pat3)
                            & (w[j+3] == pat4) & (p <= limit4);
            const bool q5 = (w[j]   == pat0) & (w[j+1] == pat1) & (w[j+2] == pat2)
                            & (w[j+3] == pat3) & (w[j+4] == pat4) & (p <= limit5);
            if (q3) bestLocal = min(bestLocal, 2 * SEQ + p);
            if (q4) bestLocal = min(bestLocal, 1 * SEQ + p);
            if (q5) bestLocal = min(bestLocal, p);
        }
    }
    // Barrier placed AFTER compute: covers s_best-init visibility without
    // stalling waves before their compare work.
    __syncthreads();
    // Matches are rare (~1e-4/position): LDS atomic traffic ~0.
    if (bestLocal != INT_MAX) atomicMin(&s_best, bestLocal);
    __syncthreads();

    if (tid < KLEN) {
        const int key = s_best;
        int v = 0;
        if (key < KEY_LIMIT) {               // mask already known nonzero
            const int n = 5 - (key >> 13);   // key / SEQ
            const int p = key & (SEQ - 1);   // key % SEQ
            // p <= L-n-K -> p+n+tid <= L-1 < SEQ
            v = tokens[base + p + n + tid];
        }
        out[b * KLEN + tid] = v;   // always write: d_out is re-poisoned
    }
}

extern "C" void kernel_launch(void* const* d_in, const int* in_sizes, int n_in,
                              void* d_out, int out_size, void* d_ws, size_t ws_size,
                              hipStream_t stream) {
    const int* num_tokens = (const int*)d_in[0];   // [B] int32
    const int* token_ids  = (const int*)d_in[1];   // [B,S] int32
    const int* cmask      = (const int*)d_in[2];   // [B] bool -> int32
    int* out              = (int*)d_out;           // [B,K] int32

    ngram_fused<<<BATCH, 1024, 0, stream>>>(num_tokens, token_ids, cmask, out);
}